// Round 1
// baseline (441.634 us; speedup 1.0000x reference)
//
#include <hip/hip_runtime.h>

#define N_NODES 25600
#define N_EDGES 204800
#define EE (N_EDGES + N_NODES)   // 230400 edges incl. self loops
#define IN_CH 6
#define HID 64
#define HEADS 4
#define G_GRAPHS 512
#define T_STEPS 50
#define OUT_DIM 30
#define NEG_SLOPE 0.2f
#define BN_INV 0.9999950000374997f   // 1/sqrt(1+1e-5)

__device__ __forceinline__ float lrelu_(float x){ return x > 0.f ? x : NEG_SLOPE * x; }
__device__ __forceinline__ float elu_(float x){ return x > 0.f ? x : expf(x) - 1.f; }
__device__ __forceinline__ float sigmoid_(float x){ return 1.f / (1.f + expf(-x)); }

// ---------------- CSR build (sort edges by dst) ----------------
__global__ void count_k(const int* __restrict__ ei, int* __restrict__ counts){
    int e = blockIdx.x * 256 + threadIdx.x;
    if (e >= EE) return;
    int dst = (e < N_EDGES) ? ei[N_EDGES + e] : (e - N_EDGES);
    atomicAdd(&counts[dst], 1);
}

__global__ void scan_k(const int* __restrict__ counts, int* __restrict__ row_ptr,
                       int* __restrict__ cursor){
    __shared__ int part[1024];
    int t = threadIdx.x;
    const int CH = N_NODES / 1024;           // 25
    int base = t * CH;
    int s = 0;
    for (int i = 0; i < CH; i++) s += counts[base + i];
    part[t] = s;
    __syncthreads();
    for (int off = 1; off < 1024; off <<= 1){
        int v = (t >= off) ? part[t - off] : 0;
        __syncthreads();
        part[t] += v;
        __syncthreads();
    }
    int run = (t > 0) ? part[t - 1] : 0;
    for (int i = 0; i < CH; i++){
        int cv = counts[base + i];
        row_ptr[base + i] = run;
        cursor[base + i]  = run;
        run += cv;
    }
    if (t == 1023) row_ptr[N_NODES] = run;
}

__global__ void scatter_k(const int* __restrict__ ei, int* __restrict__ cursor,
                          int* __restrict__ ssrc){
    int e = blockIdx.x * 256 + threadIdx.x;
    if (e >= EE) return;
    int src, dst;
    if (e < N_EDGES){ src = ei[e]; dst = ei[N_EDGES + e]; }
    else            { src = dst = e - N_EDGES; }
    int pos = atomicAdd(&cursor[dst], 1);
    ssrc[pos] = src;
}

// ---------------- GAT layer 1 transform: h1_pre = x @ W1, per-node att scores ----------------
__global__ void gat1_tr(const float* __restrict__ x, const float* __restrict__ W1,
                        const float* __restrict__ asw, const float* __restrict__ adw,
                        float* __restrict__ h1_pre, float* __restrict__ as1,
                        float* __restrict__ ad1){
    __shared__ float w[IN_CH * 256];
    int tid = threadIdx.x;
    for (int i = tid; i < IN_CH * 256; i += 256) w[i] = W1[i];
    __syncthreads();
    int wv = tid >> 6, lane = tid & 63;
    int n = blockIdx.x * 4 + wv;
    float xv[IN_CH];
    #pragma unroll
    for (int k = 0; k < IN_CH; k++) xv[k] = x[n * IN_CH + k];
    float sA[4], sD[4];
    #pragma unroll
    for (int h = 0; h < 4; h++){
        int col = h * 64 + lane;
        float acc = 0.f;
        #pragma unroll
        for (int k = 0; k < IN_CH; k++) acc += xv[k] * w[k * 256 + col];
        h1_pre[n * 256 + col] = acc;
        sA[h] = acc * asw[col];
        sD[h] = acc * adw[col];
    }
    #pragma unroll
    for (int h = 0; h < 4; h++){
        #pragma unroll
        for (int off = 32; off; off >>= 1){
            sA[h] += __shfl_xor(sA[h], off);
            sD[h] += __shfl_xor(sD[h], off);
        }
    }
    if (lane == 0){
        *(float4*)&as1[n * 4] = make_float4(sA[0], sA[1], sA[2], sA[3]);
        *(float4*)&ad1[n * 4] = make_float4(sD[0], sD[1], sD[2], sD[3]);
    }
}

// ---------------- GAT layer 1 aggregate + bias + BN + ELU ----------------
__global__ void gat1_agg(const float* __restrict__ h1_pre, const float* __restrict__ as1,
                         const float* __restrict__ ad1, const int* __restrict__ row_ptr,
                         const int* __restrict__ ssrc,
                         const float* __restrict__ b1, const float* __restrict__ g1,
                         const float* __restrict__ be1, float* __restrict__ h1_act){
    int wv = threadIdx.x >> 6, lane = threadIdx.x & 63;
    int n = blockIdx.x * 4 + wv;
    int s0 = row_ptr[n], s1 = row_ptr[n + 1];
    float4 adn = *(const float4*)&ad1[n * 4];
    float d0 = 0.f, d1 = 0.f, d2 = 0.f, d3 = 0.f;
    for (int j = s0; j < s1; j++){
        int s = ssrc[j];
        float4 as = *(const float4*)&as1[s * 4];
        d0 += expf(lrelu_(as.x + adn.x));
        d1 += expf(lrelu_(as.y + adn.y));
        d2 += expf(lrelu_(as.z + adn.z));
        d3 += expf(lrelu_(as.w + adn.w));
    }
    float i0 = 1.f / d0, i1 = 1.f / d1, i2 = 1.f / d2, i3 = 1.f / d3;
    float a0 = 0.f, a1 = 0.f, a2 = 0.f, a3 = 0.f;
    for (int j = s0; j < s1; j++){
        int s = ssrc[j];
        float4 as = *(const float4*)&as1[s * 4];
        float al0 = expf(lrelu_(as.x + adn.x)) * i0;
        float al1 = expf(lrelu_(as.y + adn.y)) * i1;
        float al2 = expf(lrelu_(as.z + adn.z)) * i2;
        float al3 = expf(lrelu_(as.w + adn.w)) * i3;
        const float* hp = h1_pre + (size_t)s * 256;
        a0 += al0 * hp[lane];
        a1 += al1 * hp[64 + lane];
        a2 += al2 * hp[128 + lane];
        a3 += al3 * hp[192 + lane];
    }
    float accs[4] = {a0, a1, a2, a3};
    #pragma unroll
    for (int h = 0; h < 4; h++){
        int col = h * 64 + lane;
        float v = accs[h] + b1[col];
        v = g1[col] * (v * BN_INV) + be1[col];
        h1_act[(size_t)n * 256 + col] = elu_(v);
    }
}

// ---------------- GAT layer 2 transform: h2_pre = h1_act @ W2, att scores ----------------
__global__ void gat2_tr(const float* __restrict__ h1_act, const float* __restrict__ W2,
                        const float* __restrict__ asw, const float* __restrict__ adw,
                        float* __restrict__ h2_pre, float* __restrict__ as2,
                        float* __restrict__ ad2){
    int tid = threadIdx.x;
    int wv = tid >> 6, lane = tid & 63;
    int n = blockIdx.x * 4 + wv;
    const float4* row4 = (const float4*)(h1_act + (size_t)n * 256);
    float acc = 0.f;
    #pragma unroll 4
    for (int k4 = 0; k4 < 64; k4++){
        float4 r = row4[k4];
        int k = k4 * 4;
        acc += r.x * W2[(k + 0) * 64 + lane];
        acc += r.y * W2[(k + 1) * 64 + lane];
        acc += r.z * W2[(k + 2) * 64 + lane];
        acc += r.w * W2[(k + 3) * 64 + lane];
    }
    h2_pre[(size_t)n * 64 + lane] = acc;
    float sA = acc * asw[lane];
    float sD = acc * adw[lane];
    #pragma unroll
    for (int off = 32; off; off >>= 1){
        sA += __shfl_xor(sA, off);
        sD += __shfl_xor(sD, off);
    }
    if (lane == 0){ as2[n] = sA; ad2[n] = sD; }
}

// ---------------- GAT layer 2 aggregate + bias + BN + ELU + scatter to x_seq ----------------
__global__ void gat2_agg(const float* __restrict__ h2_pre, const float* __restrict__ as2,
                         const float* __restrict__ ad2, const int* __restrict__ row_ptr,
                         const int* __restrict__ ssrc,
                         const float* __restrict__ b2, const float* __restrict__ g2,
                         const float* __restrict__ be2,
                         const int* __restrict__ batch, const int* __restrict__ ntime,
                         float* __restrict__ xseq){
    int wv = threadIdx.x >> 6, lane = threadIdx.x & 63;
    int n = blockIdx.x * 4 + wv;
    int s0 = row_ptr[n], s1 = row_ptr[n + 1];
    float adn = ad2[n];
    float denom = 0.f;
    for (int j = s0; j < s1; j++){
        int s = ssrc[j];
        denom += expf(lrelu_(as2[s] + adn));
    }
    float inv = 1.f / denom;
    float acc = 0.f;
    for (int j = s0; j < s1; j++){
        int s = ssrc[j];
        float a = expf(lrelu_(as2[s] + adn)) * inv;
        acc += a * h2_pre[(size_t)s * 64 + lane];
    }
    float v = acc + b2[lane];
    v = g2[lane] * (v * BN_INV) + be2[lane];
    v = elu_(v);
    int pos = batch[n] * T_STEPS + ntime[n];
    xseq[(size_t)pos * 64 + lane] = v;
}

// ---------------- LSTM over T=50 steps + final FC, one block per graph ----------------
__global__ __launch_bounds__(256, 2) void lstm_k(const float* __restrict__ xseq,
        const float* __restrict__ Wih, const float* __restrict__ Whh,
        const float* __restrict__ bih, const float* __restrict__ bhh,
        const float* __restrict__ Wfc, const float* __restrict__ bfc,
        float* __restrict__ out){
    int g = blockIdx.x;
    int j = threadIdx.x;
    __shared__ float4 xt4[16];
    __shared__ float4 h4[16];
    __shared__ float gates[256];
    float4 wih[16], whh[16];
    const float4* Wr = (const float4*)(Wih + j * 64);
    const float4* Hr = (const float4*)(Whh + j * 64);
    #pragma unroll
    for (int k = 0; k < 16; k++){ wih[k] = Wr[k]; whh[k] = Hr[k]; }
    float bsum = bih[j] + bhh[j];
    float c = 0.f;
    if (j < 16) h4[j] = make_float4(0.f, 0.f, 0.f, 0.f);
    __syncthreads();
    const float4* xg = (const float4*)(xseq + (size_t)g * T_STEPS * 64);
    for (int t = 0; t < T_STEPS; t++){
        if (j < 16) xt4[j] = xg[t * 16 + j];
        __syncthreads();
        float acc = bsum;
        #pragma unroll
        for (int k = 0; k < 16; k++){
            float4 xv = xt4[k]; float4 wv = wih[k];
            acc += wv.x * xv.x; acc += wv.y * xv.y;
            acc += wv.z * xv.z; acc += wv.w * xv.w;
            float4 hv = h4[k]; float4 wh = whh[k];
            acc += wh.x * hv.x; acc += wh.y * hv.y;
            acc += wh.z * hv.z; acc += wh.w * hv.w;
        }
        gates[j] = acc;
        __syncthreads();
        if (j < 64){
            float iv = gates[j], fv = gates[64 + j], gv = gates[128 + j], ov = gates[192 + j];
            c = sigmoid_(fv) * c + sigmoid_(iv) * tanhf(gv);
            float hn = sigmoid_(ov) * tanhf(c);
            ((float*)h4)[j] = hn;
        }
        __syncthreads();
    }
    if (j < OUT_DIM){
        float acc = bfc[j];
        const float* hf = (const float*)h4;
        #pragma unroll
        for (int k = 0; k < 64; k++) acc += hf[k] * Wfc[k * OUT_DIM + j];
        out[g * OUT_DIM + j] = acc;
    }
}

extern "C" void kernel_launch(void* const* d_in, const int* in_sizes, int n_in,
                              void* d_out, int out_size, void* d_ws, size_t ws_size,
                              hipStream_t stream){
    const float* x    = (const float*)d_in[0];
    const int*   ei   = (const int*)  d_in[1];
    const int*   batch= (const int*)  d_in[2];
    const int*   ntime= (const int*)  d_in[3];
    const float* W1   = (const float*)d_in[4];
    const float* as1w = (const float*)d_in[5];
    const float* ad1w = (const float*)d_in[6];
    const float* b1   = (const float*)d_in[7];
    const float* g1   = (const float*)d_in[8];
    const float* be1  = (const float*)d_in[9];
    const float* W2   = (const float*)d_in[10];
    const float* as2w = (const float*)d_in[11];
    const float* ad2w = (const float*)d_in[12];
    const float* b2   = (const float*)d_in[13];
    const float* g2   = (const float*)d_in[14];
    const float* be2  = (const float*)d_in[15];
    const float* Wih  = (const float*)d_in[16];
    const float* Whh  = (const float*)d_in[17];
    const float* bih  = (const float*)d_in[18];
    const float* bhh  = (const float*)d_in[19];
    const float* Wfc  = (const float*)d_in[20];
    const float* bfc  = (const float*)d_in[21];
    float* out = (float*)d_out;

    char* w = (char*)d_ws;
    auto alloc = [&](size_t bytes)->char*{
        char* p = w;
        w += (bytes + 255) & ~size_t(255);
        return p;
    };
    float* h1_pre = (float*)alloc((size_t)N_NODES * 256 * 4);
    float* h1_act = (float*)alloc((size_t)N_NODES * 256 * 4);
    float* h2_pre = (float*)alloc((size_t)N_NODES * 64 * 4);
    float* xseq   = (float*)alloc((size_t)G_GRAPHS * T_STEPS * 64 * 4);
    float* as1    = (float*)alloc((size_t)N_NODES * 4 * 4);
    float* ad1    = (float*)alloc((size_t)N_NODES * 4 * 4);
    float* as2    = (float*)alloc((size_t)N_NODES * 4);
    float* ad2    = (float*)alloc((size_t)N_NODES * 4);
    int* counts   = (int*)alloc((size_t)N_NODES * 4);
    int* row_ptr  = (int*)alloc((size_t)(N_NODES + 1) * 4);
    int* cursor   = (int*)alloc((size_t)N_NODES * 4);
    int* ssrc     = (int*)alloc((size_t)EE * 4);

    hipMemsetAsync(counts, 0, (size_t)N_NODES * 4, stream);
    count_k  <<<(EE + 255) / 256, 256, 0, stream>>>(ei, counts);
    scan_k   <<<1, 1024, 0, stream>>>(counts, row_ptr, cursor);
    scatter_k<<<(EE + 255) / 256, 256, 0, stream>>>(ei, cursor, ssrc);
    gat1_tr  <<<N_NODES / 4, 256, 0, stream>>>(x, W1, as1w, ad1w, h1_pre, as1, ad1);
    gat1_agg <<<N_NODES / 4, 256, 0, stream>>>(h1_pre, as1, ad1, row_ptr, ssrc, b1, g1, be1, h1_act);
    gat2_tr  <<<N_NODES / 4, 256, 0, stream>>>(h1_act, W2, as2w, ad2w, h2_pre, as2, ad2);
    gat2_agg <<<N_NODES / 4, 256, 0, stream>>>(h2_pre, as2, ad2, row_ptr, ssrc, b2, g2, be2, batch, ntime, xseq);
    lstm_k   <<<G_GRAPHS, 256, 0, stream>>>(xseq, Wih, Whh, bih, bhh, Wfc, bfc, out);
}

// Round 2
// 315.431 us; speedup vs baseline: 1.4001x; 1.4001x over previous
//
#include <hip/hip_runtime.h>

#define N_NODES 25600
#define N_EDGES 204800
#define EE (N_EDGES + N_NODES)   // 230400 edges incl. self loops
#define IN_CH 6
#define HID 64
#define HEADS 4
#define G_GRAPHS 512
#define T_STEPS 50
#define OUT_DIM 30
#define NEG_SLOPE 0.2f
#define BN_INV 0.9999950000374997f   // 1/sqrt(1+1e-5)

__device__ __forceinline__ float lrelu_(float x){ return x > 0.f ? x : NEG_SLOPE * x; }
__device__ __forceinline__ float elu_(float x){ return x > 0.f ? x : __expf(x) - 1.f; }
__device__ __forceinline__ float sigmoid_(float x){ return 1.f / (1.f + __expf(-x)); }

// ---------------- CSR build (sort edges by dst) ----------------
__global__ void count_k(const int* __restrict__ ei, int* __restrict__ counts){
    int e = blockIdx.x * 256 + threadIdx.x;
    if (e >= EE) return;
    int dst = (e < N_EDGES) ? ei[N_EDGES + e] : (e - N_EDGES);
    atomicAdd(&counts[dst], 1);
}

__global__ void scan_k(const int* __restrict__ counts, int* __restrict__ row_ptr,
                       int* __restrict__ cursor){
    __shared__ int part[1024];
    int t = threadIdx.x;
    const int CH = N_NODES / 1024;           // 25
    int base = t * CH;
    int s = 0;
    for (int i = 0; i < CH; i++) s += counts[base + i];
    part[t] = s;
    __syncthreads();
    for (int off = 1; off < 1024; off <<= 1){
        int v = (t >= off) ? part[t - off] : 0;
        __syncthreads();
        part[t] += v;
        __syncthreads();
    }
    int run = (t > 0) ? part[t - 1] : 0;
    for (int i = 0; i < CH; i++){
        int cv = counts[base + i];
        row_ptr[base + i] = run;
        cursor[base + i]  = run;
        run += cv;
    }
    if (t == 1023) row_ptr[N_NODES] = run;
}

__global__ void scatter_k(const int* __restrict__ ei, int* __restrict__ cursor,
                          int* __restrict__ ssrc){
    int e = blockIdx.x * 256 + threadIdx.x;
    if (e >= EE) return;
    int src, dst;
    if (e < N_EDGES){ src = ei[e]; dst = ei[N_EDGES + e]; }
    else            { src = dst = e - N_EDGES; }
    int pos = atomicAdd(&cursor[dst], 1);
    ssrc[pos] = src;
}

// ---------------- GAT layer 1 transform: h1_pre = x @ W1, per-node att scores ----------------
__global__ void gat1_tr(const float* __restrict__ x, const float* __restrict__ W1,
                        const float* __restrict__ asw, const float* __restrict__ adw,
                        float* __restrict__ h1_pre, float* __restrict__ as1,
                        float* __restrict__ ad1){
    __shared__ float w[IN_CH * 256];
    int tid = threadIdx.x;
    for (int i = tid; i < IN_CH * 256; i += 256) w[i] = W1[i];
    __syncthreads();
    int wv = tid >> 6, lane = tid & 63;
    int n = blockIdx.x * 4 + wv;
    float xv[IN_CH];
    #pragma unroll
    for (int k = 0; k < IN_CH; k++) xv[k] = x[n * IN_CH + k];
    float sA[4], sD[4];
    #pragma unroll
    for (int h = 0; h < 4; h++){
        int col = h * 64 + lane;
        float acc = 0.f;
        #pragma unroll
        for (int k = 0; k < IN_CH; k++) acc += xv[k] * w[k * 256 + col];
        h1_pre[n * 256 + col] = acc;
        sA[h] = acc * asw[col];
        sD[h] = acc * adw[col];
    }
    #pragma unroll
    for (int h = 0; h < 4; h++){
        #pragma unroll
        for (int off = 32; off; off >>= 1){
            sA[h] += __shfl_xor(sA[h], off);
            sD[h] += __shfl_xor(sD[h], off);
        }
    }
    if (lane == 0){
        *(float4*)&as1[n * 4] = make_float4(sA[0], sA[1], sA[2], sA[3]);
        *(float4*)&ad1[n * 4] = make_float4(sD[0], sD[1], sD[2], sD[3]);
    }
}

// ---------------- GAT layer 1 aggregate (single-pass softmax) + bias + BN + ELU ----------------
__global__ void gat1_agg(const float* __restrict__ h1_pre, const float* __restrict__ as1,
                         const float* __restrict__ ad1, const int* __restrict__ row_ptr,
                         const int* __restrict__ ssrc,
                         const float* __restrict__ b1, const float* __restrict__ g1,
                         const float* __restrict__ be1, float* __restrict__ h1_act){
    int wv = threadIdx.x >> 6, lane = threadIdx.x & 63;
    int n = blockIdx.x * 4 + wv;
    int s0 = row_ptr[n], s1 = row_ptr[n + 1];
    float4 adn = *(const float4*)&ad1[n * 4];
    float d0 = 0.f, d1 = 0.f, d2 = 0.f, d3 = 0.f;
    float a0 = 0.f, a1 = 0.f, a2 = 0.f, a3 = 0.f;
    // out = (sum_j e_j * h_j) / (sum_j e_j) -- single pass
    for (int j = s0; j < s1; j++){
        int s = ssrc[j];
        float4 as = *(const float4*)&as1[s * 4];
        float e0 = __expf(lrelu_(as.x + adn.x));
        float e1 = __expf(lrelu_(as.y + adn.y));
        float e2 = __expf(lrelu_(as.z + adn.z));
        float e3 = __expf(lrelu_(as.w + adn.w));
        d0 += e0; d1 += e1; d2 += e2; d3 += e3;
        const float* hp = h1_pre + (size_t)s * 256;
        a0 += e0 * hp[lane];
        a1 += e1 * hp[64 + lane];
        a2 += e2 * hp[128 + lane];
        a3 += e3 * hp[192 + lane];
    }
    float accs[4] = {a0 / d0, a1 / d1, a2 / d2, a3 / d3};
    #pragma unroll
    for (int h = 0; h < 4; h++){
        int col = h * 64 + lane;
        float v = accs[h] + b1[col];
        v = g1[col] * (v * BN_INV) + be1[col];
        h1_act[(size_t)n * 256 + col] = elu_(v);
    }
}

// ---------------- GAT layer 2 transform: tiled SGEMM h2_pre = h1_act @ W2 + fused scores ----
// C[25600 x 64] = A[25600 x 256] * B[256 x 64]; 64-row tile per block, KT=32, 4x4 micro-tile.
#define TM 64
#define KT 32
#define APAD 4   // A-tile stride 36: rg-groups land 16 banks apart -> 2-way (free)
__global__ __launch_bounds__(256) void gat2_tr(const float* __restrict__ h1_act,
                        const float* __restrict__ W2,
                        const float* __restrict__ asw, const float* __restrict__ adw,
                        float* __restrict__ h2_pre, float* __restrict__ as2,
                        float* __restrict__ ad2){
    __shared__ float As[TM][KT + APAD];
    __shared__ float Bs[KT][64];
    int tx = threadIdx.x;
    int rg = tx >> 4;        // 0..15 (row group; 16 consecutive lanes share rows)
    int cg = tx & 15;        // 0..15 (col group)
    int r0 = rg * 4, c0 = cg * 4;
    int rowBase = blockIdx.x * TM;
    float acc[4][4] = {};
    for (int k0 = 0; k0 < 256; k0 += KT){
        #pragma unroll
        for (int it = 0; it < 2; it++){
            int i = tx + it * 256;
            int row = i >> 3;            // 0..63
            int c4  = (i & 7) * 4;       // 0..28
            *(float4*)&As[row][c4] =
                *(const float4*)(h1_act + (size_t)(rowBase + row) * 256 + k0 + c4);
        }
        #pragma unroll
        for (int it = 0; it < 2; it++){
            int i = tx + it * 256;
            int row = i >> 4;            // 0..31
            int c4  = (i & 15) * 4;
            *(float4*)&Bs[row][c4] = *(const float4*)(W2 + (size_t)(k0 + row) * 64 + c4);
        }
        __syncthreads();
        #pragma unroll
        for (int kq = 0; kq < KT; kq += 4){
            float4 b0 = *(float4*)&Bs[kq + 0][c0];
            float4 b1v = *(float4*)&Bs[kq + 1][c0];
            float4 b2v = *(float4*)&Bs[kq + 2][c0];
            float4 b3 = *(float4*)&Bs[kq + 3][c0];
            #pragma unroll
            for (int i = 0; i < 4; i++){
                float4 a = *(float4*)&As[r0 + i][kq];
                acc[i][0] += a.x * b0.x + a.y * b1v.x + a.z * b2v.x + a.w * b3.x;
                acc[i][1] += a.x * b0.y + a.y * b1v.y + a.z * b2v.y + a.w * b3.y;
                acc[i][2] += a.x * b0.z + a.y * b1v.z + a.z * b2v.z + a.w * b3.z;
                acc[i][3] += a.x * b0.w + a.y * b1v.w + a.z * b2v.w + a.w * b3.w;
            }
        }
        __syncthreads();
    }
    float aw0 = asw[c0], aw1 = asw[c0+1], aw2 = asw[c0+2], aw3 = asw[c0+3];
    float dw0 = adw[c0], dw1 = adw[c0+1], dw2 = adw[c0+2], dw3 = adw[c0+3];
    #pragma unroll
    for (int i = 0; i < 4; i++){
        int row = rowBase + r0 + i;
        *(float4*)(h2_pre + (size_t)row * 64 + c0) =
            make_float4(acc[i][0], acc[i][1], acc[i][2], acc[i][3]);
        float sA = acc[i][0]*aw0 + acc[i][1]*aw1 + acc[i][2]*aw2 + acc[i][3]*aw3;
        float sD = acc[i][0]*dw0 + acc[i][1]*dw1 + acc[i][2]*dw2 + acc[i][3]*dw3;
        #pragma unroll
        for (int off = 8; off; off >>= 1){
            sA += __shfl_xor(sA, off);
            sD += __shfl_xor(sD, off);
        }
        if (cg == 0){ as2[row] = sA; ad2[row] = sD; }
    }
}

// ---------------- GAT layer 2 aggregate (single-pass) + bias + BN + ELU + scatter ----------------
__global__ void gat2_agg(const float* __restrict__ h2_pre, const float* __restrict__ as2,
                         const float* __restrict__ ad2, const int* __restrict__ row_ptr,
                         const int* __restrict__ ssrc,
                         const float* __restrict__ b2, const float* __restrict__ g2,
                         const float* __restrict__ be2,
                         const int* __restrict__ batch, const int* __restrict__ ntime,
                         float* __restrict__ xseq){
    int wv = threadIdx.x >> 6, lane = threadIdx.x & 63;
    int n = blockIdx.x * 4 + wv;
    int s0 = row_ptr[n], s1 = row_ptr[n + 1];
    float adn = ad2[n];
    float denom = 0.f, acc = 0.f;
    for (int j = s0; j < s1; j++){
        int s = ssrc[j];
        float e = __expf(lrelu_(as2[s] + adn));
        denom += e;
        acc += e * h2_pre[(size_t)s * 64 + lane];
    }
    float v = acc / denom + b2[lane];
    v = g2[lane] * (v * BN_INV) + be2[lane];
    v = elu_(v);
    int pos = batch[n] * T_STEPS + ntime[n];
    xseq[(size_t)pos * 64 + lane] = v;
}

// ---------------- LSTM over T=50 steps + final FC, one block per graph ----------------
__global__ __launch_bounds__(256, 2) void lstm_k(const float* __restrict__ xseq,
        const float* __restrict__ Wih, const float* __restrict__ Whh,
        const float* __restrict__ bih, const float* __restrict__ bhh,
        const float* __restrict__ Wfc, const float* __restrict__ bfc,
        float* __restrict__ out){
    int g = blockIdx.x;
    int j = threadIdx.x;
    __shared__ float4 xt4[16];
    __shared__ float4 h4[16];
    __shared__ float gates[256];
    float4 wih[16], whh[16];
    const float4* Wr = (const float4*)(Wih + j * 64);
    const float4* Hr = (const float4*)(Whh + j * 64);
    #pragma unroll
    for (int k = 0; k < 16; k++){ wih[k] = Wr[k]; whh[k] = Hr[k]; }
    float bsum = bih[j] + bhh[j];
    float c = 0.f;
    if (j < 16) h4[j] = make_float4(0.f, 0.f, 0.f, 0.f);
    __syncthreads();
    const float4* xg = (const float4*)(xseq + (size_t)g * T_STEPS * 64);
    for (int t = 0; t < T_STEPS; t++){
        if (j < 16) xt4[j] = xg[t * 16 + j];
        __syncthreads();
        float acc = bsum;
        #pragma unroll
        for (int k = 0; k < 16; k++){
            float4 xv = xt4[k]; float4 wv = wih[k];
            acc += wv.x * xv.x; acc += wv.y * xv.y;
            acc += wv.z * xv.z; acc += wv.w * xv.w;
            float4 hv = h4[k]; float4 wh = whh[k];
            acc += wh.x * hv.x; acc += wh.y * hv.y;
            acc += wh.z * hv.z; acc += wh.w * hv.w;
        }
        gates[j] = acc;
        __syncthreads();
        if (j < 64){
            float iv = gates[j], fv = gates[64 + j], gv = gates[128 + j], ov = gates[192 + j];
            c = sigmoid_(fv) * c + sigmoid_(iv) * tanhf(gv);
            float hn = sigmoid_(ov) * tanhf(c);
            ((float*)h4)[j] = hn;
        }
        __syncthreads();
    }
    if (j < OUT_DIM){
        float acc = bfc[j];
        const float* hf = (const float*)h4;
        #pragma unroll
        for (int k = 0; k < 64; k++) acc += hf[k] * Wfc[k * OUT_DIM + j];
        out[g * OUT_DIM + j] = acc;
    }
}

extern "C" void kernel_launch(void* const* d_in, const int* in_sizes, int n_in,
                              void* d_out, int out_size, void* d_ws, size_t ws_size,
                              hipStream_t stream){
    const float* x    = (const float*)d_in[0];
    const int*   ei   = (const int*)  d_in[1];
    const int*   batch= (const int*)  d_in[2];
    const int*   ntime= (const int*)  d_in[3];
    const float* W1   = (const float*)d_in[4];
    const float* as1w = (const float*)d_in[5];
    const float* ad1w = (const float*)d_in[6];
    const float* b1   = (const float*)d_in[7];
    const float* g1   = (const float*)d_in[8];
    const float* be1  = (const float*)d_in[9];
    const float* W2   = (const float*)d_in[10];
    const float* as2w = (const float*)d_in[11];
    const float* ad2w = (const float*)d_in[12];
    const float* b2   = (const float*)d_in[13];
    const float* g2   = (const float*)d_in[14];
    const float* be2  = (const float*)d_in[15];
    const float* Wih  = (const float*)d_in[16];
    const float* Whh  = (const float*)d_in[17];
    const float* bih  = (const float*)d_in[18];
    const float* bhh  = (const float*)d_in[19];
    const float* Wfc  = (const float*)d_in[20];
    const float* bfc  = (const float*)d_in[21];
    float* out = (float*)d_out;

    char* w = (char*)d_ws;
    auto alloc = [&](size_t bytes)->char*{
        char* p = w;
        w += (bytes + 255) & ~size_t(255);
        return p;
    };
    float* h1_pre = (float*)alloc((size_t)N_NODES * 256 * 4);
    float* h1_act = (float*)alloc((size_t)N_NODES * 256 * 4);
    float* h2_pre = (float*)alloc((size_t)N_NODES * 64 * 4);
    float* xseq   = (float*)alloc((size_t)G_GRAPHS * T_STEPS * 64 * 4);
    float* as1    = (float*)alloc((size_t)N_NODES * 4 * 4);
    float* ad1    = (float*)alloc((size_t)N_NODES * 4 * 4);
    float* as2    = (float*)alloc((size_t)N_NODES * 4);
    float* ad2    = (float*)alloc((size_t)N_NODES * 4);
    int* counts   = (int*)alloc((size_t)N_NODES * 4);
    int* row_ptr  = (int*)alloc((size_t)(N_NODES + 1) * 4);
    int* cursor   = (int*)alloc((size_t)N_NODES * 4);
    int* ssrc     = (int*)alloc((size_t)EE * 4);

    hipMemsetAsync(counts, 0, (size_t)N_NODES * 4, stream);
    count_k  <<<(EE + 255) / 256, 256, 0, stream>>>(ei, counts);
    scan_k   <<<1, 1024, 0, stream>>>(counts, row_ptr, cursor);
    scatter_k<<<(EE + 255) / 256, 256, 0, stream>>>(ei, cursor, ssrc);
    gat1_tr  <<<N_NODES / 4, 256, 0, stream>>>(x, W1, as1w, ad1w, h1_pre, as1, ad1);
    gat1_agg <<<N_NODES / 4, 256, 0, stream>>>(h1_pre, as1, ad1, row_ptr, ssrc, b1, g1, be1, h1_act);
    gat2_tr  <<<N_NODES / TM, 256, 0, stream>>>(h1_act, W2, as2w, ad2w, h2_pre, as2, ad2);
    gat2_agg <<<N_NODES / 4, 256, 0, stream>>>(h2_pre, as2, ad2, row_ptr, ssrc, b2, g2, be2, batch, ntime, xseq);
    lstm_k   <<<G_GRAPHS, 256, 0, stream>>>(xseq, Wih, Whh, bih, bhh, Wfc, bfc, out);
}